// Round 1
// baseline (301.434 us; speedup 1.0000x reference)
//
#include <hip/hip_runtime.h>
#include <hip/hip_bf16.h>

// Pattention fused kernel, round 1.
// out[m,n] = (sqrt(P)/||gelu(X K^T)[m,:]||) * (gelu(X K^T) @ V)[m,n]
// M=16384 (B*T), D=512, P=4096. bf16 MFMA (16x16x32), fp32 accum.

typedef __attribute__((ext_vector_type(8))) short bf16x8;   // 8 bf16 = 4 VGPR
typedef __attribute__((ext_vector_type(4))) float f32x4;    // MFMA C/D

static constexpr int M_TOTAL = 16384;
static constexpr int DDIM    = 512;
static constexpr int PDIM    = 4096;
static constexpr int BM      = 64;    // rows per block
static constexpr int BP      = 64;    // P-tile
static constexpr int KPAD    = 264;   // K_lds row elems (256 + 8) -> 528B, 16B-multiple
static constexpr int GPAD    = 72;    // g_lds row elems (64 + 8)  -> 144B, 16B-multiple

__device__ __forceinline__ unsigned short f2bf(float f) {
    union { float f; unsigned u; } v; v.f = f;
    unsigned r = v.u + 0x7FFFu + ((v.u >> 16) & 1u);   // RNE
    return (unsigned short)(r >> 16);
}

// tanh-form GELU: x * sigmoid(2 * x * (c0 + c1 x^2)); |err vs exact| < 1e-3
__device__ __forceinline__ float gelu_f(float x) {
    float t2 = 2.0f * x * (0.7978845608028654f + 0.035677408136300125f * x * x);
    return x / (1.0f + __expf(-t2));
}

// ---------- convert key_tokens fp32 -> bf16 row-major [4096][512] ----------
__global__ void conv_k(const float* __restrict__ kin, unsigned short* __restrict__ kbf) {
    int i = (blockIdx.x * 256 + threadIdx.x) * 4;   // grid covers 2M elems exactly
    float4 v = *reinterpret_cast<const float4*>(kin + i);
    ushort4 o;
    o.x = f2bf(v.x); o.y = f2bf(v.y); o.z = f2bf(v.z); o.w = f2bf(v.w);
    *reinterpret_cast<ushort4*>(kbf + i) = o;
}

// ---------- convert value_tokens fp32 [4096][512] -> fragment-blocked bf16 ----------
// Layout: frag block (pb in [0,128) over p/32, nb in [0,32) over n/16), 64 lanes x 8 elems:
//   vt2[ ((pb*32 + nb)*64 + lane)*8 + j ] = V[ pb*32 + (lane>>4)*8 + j ][ nb*16 + (lane&15) ]
// GEMM2 B-fragment load is then a single coalesced 16B/lane global read.
__global__ void conv_vt2(const float* __restrict__ vin, unsigned short* __restrict__ vt2) {
    int tid  = blockIdx.x * 256 + threadIdx.x;  // 262144 total
    int lane = tid & 63;
    int blk  = tid >> 6;
    int nb = blk & 31;
    int pb = blk >> 5;
    int p0 = pb * 32 + ((lane >> 4) << 3);
    int n  = nb * 16 + (lane & 15);
    ushort4 a, b;
    a.x = f2bf(vin[(p0 + 0) * DDIM + n]);
    a.y = f2bf(vin[(p0 + 1) * DDIM + n]);
    a.z = f2bf(vin[(p0 + 2) * DDIM + n]);
    a.w = f2bf(vin[(p0 + 3) * DDIM + n]);
    b.x = f2bf(vin[(p0 + 4) * DDIM + n]);
    b.y = f2bf(vin[(p0 + 5) * DDIM + n]);
    b.z = f2bf(vin[(p0 + 6) * DDIM + n]);
    b.w = f2bf(vin[(p0 + 7) * DDIM + n]);
    *reinterpret_cast<ushort4*>(vt2 + tid * 8 + 0) = a;
    *reinterpret_cast<ushort4*>(vt2 + tid * 8 + 4) = b;
}

// ---------- fused kernel: 256 blocks x 512 threads (8 waves) ----------
// Wave roles: GEMM1 (S = X K^T): 4x2 wave grid, each wave a 16x32 S sub-tile.
//             GEMM2 (O += g V):  wave w owns output cols [64w, 64w+64).
__global__ __launch_bounds__(512, 2) void fused_pattn(
    const float* __restrict__ x,              // [16384][512] fp32
    const unsigned short* __restrict__ kbf,   // [4096][512] bf16
    const unsigned short* __restrict__ vt2,   // fragment-blocked bf16
    float* __restrict__ out)                  // [16384][512] fp32
{
    __shared__ unsigned short k_lds[BM * KPAD];  // 33792 B
    __shared__ unsigned short g_lds[BM * GPAD];  //  9216 B
    __shared__ float ss_lds[BM];

    const int tid  = threadIdx.x;
    const int lane = tid & 63;
    const int w    = tid >> 6;       // wave 0..7
    const int wr   = w >> 1;         // GEMM1 wave row (0..3)
    const int wc   = w & 1;          // GEMM1 wave col (0..1)
    const int l15  = lane & 15;
    const int l4   = lane >> 4;
    const int m_base = blockIdx.x * BM;

    if (tid < BM) ss_lds[tid] = 0.0f;

    // ---- load X A-fragments once: 16 frags x 8 bf16 (A[l&15][(l>>4)*8+j]) ----
    bf16x8 xf[16];
    {
        const float* xrow = x + (size_t)(m_base + wr * 16 + l15) * DDIM + l4 * 8;
        #pragma unroll
        for (int db = 0; db < 16; ++db) {
            float4 a = *reinterpret_cast<const float4*>(xrow + db * 32);
            float4 b = *reinterpret_cast<const float4*>(xrow + db * 32 + 4);
            bf16x8 f;
            f[0] = (short)f2bf(a.x); f[1] = (short)f2bf(a.y);
            f[2] = (short)f2bf(a.z); f[3] = (short)f2bf(a.w);
            f[4] = (short)f2bf(b.x); f[5] = (short)f2bf(b.y);
            f[6] = (short)f2bf(b.z); f[7] = (short)f2bf(b.w);
            xf[db] = f;
        }
    }

    f32x4 zero4 = {0.0f, 0.0f, 0.0f, 0.0f};
    f32x4 oacc[4][4];
    #pragma unroll
    for (int i = 0; i < 4; ++i)
        #pragma unroll
        for (int j = 0; j < 4; ++j) oacc[i][j] = zero4;
    float ss[4] = {0.0f, 0.0f, 0.0f, 0.0f};

    for (int pt = 0; pt < PDIM / BP; ++pt) {
        const int p0 = pt * BP;
        f32x4 sacc[2]; sacc[0] = zero4; sacc[1] = zero4;

        // ---- GEMM1: S[64x64] = X[64x512] @ K[p0..p0+64][512]^T, d in 2 chunks of 256
        #pragma unroll
        for (int dc = 0; dc < 2; ++dc) {
            __syncthreads();   // k_lds free (prev readers done)
            #pragma unroll
            for (int it = 0; it < 4; ++it) {      // stage 64x256 bf16 chunk
                int idx = tid + it * 512;
                int row = idx >> 5;
                int c8  = (idx & 31) << 3;
                bf16x8 kv = *reinterpret_cast<const bf16x8*>(
                    kbf + (size_t)(p0 + row) * DDIM + dc * 256 + c8);
                *reinterpret_cast<bf16x8*>(&k_lds[row * KPAD + c8]) = kv;
            }
            __syncthreads();
            #pragma unroll
            for (int db = 0; db < 8; ++db) {
                #pragma unroll
                for (int f = 0; f < 2; ++f) {
                    bf16x8 kb = *reinterpret_cast<const bf16x8*>(
                        &k_lds[(wc * 32 + f * 16 + l15) * KPAD + db * 32 + l4 * 8]);
                    sacc[f] = __builtin_amdgcn_mfma_f32_16x16x32_bf16(
                        xf[dc * 8 + db], kb, sacc[f], 0, 0, 0);
                }
            }
        }

        // ---- GELU + sumsq + write g to LDS (bf16) ----
        #pragma unroll
        for (int f = 0; f < 2; ++f) {
            #pragma unroll
            for (int r = 0; r < 4; ++r) {
                float g = gelu_f(sacc[f][r]);
                ss[r] += g * g;
                int m_l = wr * 16 + l4 * 4 + r;
                int p_l = wc * 32 + f * 16 + l15;
                g_lds[m_l * GPAD + p_l] = f2bf(g);
            }
        }
        __syncthreads();   // g visible to all waves

        // ---- GEMM2: O[64x512] += g[64x64] @ V[64x512] (B-frags direct from global)
        #pragma unroll
        for (int ks = 0; ks < 2; ++ks) {
            bf16x8 ag[4], bg[4];
            #pragma unroll
            for (int mf = 0; mf < 4; ++mf)
                ag[mf] = *reinterpret_cast<const bf16x8*>(
                    &g_lds[(mf * 16 + l15) * GPAD + ks * 32 + l4 * 8]);
            const int pb = (p0 >> 5) + ks;
            #pragma unroll
            for (int nf = 0; nf < 4; ++nf) {
                int nb = w * 4 + nf;
                bg[nf] = *reinterpret_cast<const bf16x8*>(
                    vt2 + ((size_t)(pb * 32 + nb) * 64 + lane) * 8);
            }
            #pragma unroll
            for (int mf = 0; mf < 4; ++mf)
                #pragma unroll
                for (int nf = 0; nf < 4; ++nf)
                    oacc[mf][nf] = __builtin_amdgcn_mfma_f32_16x16x32_bf16(
                        ag[mf], bg[nf], oacc[mf][nf], 0, 0, 0);
        }
        // no end barrier: next tile's staging barrier protects k_lds/g_lds
    }

    // ---- reduce sumsq across the 16 lanes sharing rows, then across wave-cols ----
    #pragma unroll
    for (int r = 0; r < 4; ++r) {
        float v = ss[r];
        v += __shfl_xor(v, 1, 64);
        v += __shfl_xor(v, 2, 64);
        v += __shfl_xor(v, 4, 64);
        v += __shfl_xor(v, 8, 64);
        if (l15 == 0) atomicAdd(&ss_lds[wr * 16 + l4 * 4 + r], v);
    }
    __syncthreads();

    // ---- epilogue: out = O * sqrt(P)/sqrt(ss) ----
    #pragma unroll
    for (int mf = 0; mf < 4; ++mf) {
        #pragma unroll
        for (int r = 0; r < 4; ++r) {
            int m_l = mf * 16 + l4 * 4 + r;
            float scale = 64.0f * rsqrtf(ss_lds[m_l]);
            float* orow = out + (size_t)(m_base + m_l) * DDIM + w * 64 + l15;
            #pragma unroll
            for (int nf = 0; nf < 4; ++nf)
                orow[nf * 16] = oacc[mf][nf][r] * scale;
        }
    }
}

extern "C" void kernel_launch(void* const* d_in, const int* in_sizes, int n_in,
                              void* d_out, int out_size, void* d_ws, size_t ws_size,
                              hipStream_t stream) {
    const float* x = (const float*)d_in[0];   // [4,4096,512] = [16384][512]
    const float* k = (const float*)d_in[1];   // [4096][512]
    const float* v = (const float*)d_in[2];   // [4096][512]
    float* out = (float*)d_out;               // [16384][512]

    unsigned short* kbf = (unsigned short*)d_ws;            // 4 MB
    unsigned short* vt2 = kbf + (size_t)PDIM * DDIM;        // 4 MB

    conv_k  <<<dim3(2048), dim3(256), 0, stream>>>(k, kbf);
    conv_vt2<<<dim3(1024), dim3(256), 0, stream>>>(v, vt2);
    fused_pattn<<<dim3(M_TOTAL / BM), dim3(512), 0, stream>>>(x, kbf, vt2, out);
}

// Round 2
// 226.986 us; speedup vs baseline: 1.3280x; 1.3280x over previous
//
#include <hip/hip_runtime.h>
#include <hip/hip_bf16.h>

// Pattention fused kernel, round 2: counted-vmcnt pipeline.
// out[m,n] = (sqrt(P)/||gelu(X K^T)[m,:]||) * (gelu(X K^T) @ V)[m,n]
// M=16384 (B*T), D=512, P=4096. bf16 MFMA (16x16x32), fp32 accum.

typedef __attribute__((ext_vector_type(8))) short bf16x8;   // 8 bf16 = 4 VGPR
typedef __attribute__((ext_vector_type(4))) float f32x4;    // MFMA C/D

static constexpr int M_TOTAL = 16384;
static constexpr int DDIM    = 512;
static constexpr int PDIM    = 4096;
static constexpr int BM      = 64;    // rows per block
static constexpr int BP      = 64;    // P-tile
static constexpr int GPAD    = 72;    // g_lds row elems (64 + 8) -> 144B

#define AS1C(p) ((const __attribute__((address_space(1))) void*)(p))
#define AS3(p)  ((__attribute__((address_space(3))) void*)(p))

__device__ __forceinline__ unsigned short f2bf(float f) {
    union { float f; unsigned u; } v; v.f = f;
    unsigned r = v.u + 0x7FFFu + ((v.u >> 16) & 1u);   // RNE
    return (unsigned short)(r >> 16);
}

// tanh-form GELU: x * sigmoid(2 * x * (c0 + c1 x^2)); |err vs exact| < 1e-3
__device__ __forceinline__ float gelu_f(float x) {
    float t2 = 2.0f * x * (0.7978845608028654f + 0.035677408136300125f * x * x);
    return x / (1.0f + __expf(-t2));
}

// ---------- convert key_tokens fp32 -> bf16 row-major [4096][512] ----------
__global__ void conv_k(const float* __restrict__ kin, unsigned short* __restrict__ kbf) {
    int i = (blockIdx.x * 256 + threadIdx.x) * 4;
    float4 v = *reinterpret_cast<const float4*>(kin + i);
    ushort4 o;
    o.x = f2bf(v.x); o.y = f2bf(v.y); o.z = f2bf(v.z); o.w = f2bf(v.w);
    *reinterpret_cast<ushort4*>(kbf + i) = o;
}

// ---------- convert value_tokens fp32 [4096][512] -> fragment-blocked bf16 ----------
//   vt2[ ((pb*32 + nb)*64 + lane)*8 + j ] = V[ pb*32 + (lane>>4)*8 + j ][ nb*16 + (lane&15) ]
__global__ void conv_vt2(const float* __restrict__ vin, unsigned short* __restrict__ vt2) {
    int tid  = blockIdx.x * 256 + threadIdx.x;  // 262144 total
    int lane = tid & 63;
    int blk  = tid >> 6;
    int nb = blk & 31;
    int pb = blk >> 5;
    int p0 = pb * 32 + ((lane >> 4) << 3);
    int n  = nb * 16 + (lane & 15);
    ushort4 a, b;
    a.x = f2bf(vin[(p0 + 0) * DDIM + n]);
    a.y = f2bf(vin[(p0 + 1) * DDIM + n]);
    a.z = f2bf(vin[(p0 + 2) * DDIM + n]);
    a.w = f2bf(vin[(p0 + 3) * DDIM + n]);
    b.x = f2bf(vin[(p0 + 4) * DDIM + n]);
    b.y = f2bf(vin[(p0 + 5) * DDIM + n]);
    b.z = f2bf(vin[(p0 + 6) * DDIM + n]);
    b.w = f2bf(vin[(p0 + 7) * DDIM + n]);
    *reinterpret_cast<ushort4*>(vt2 + tid * 8 + 0) = a;
    *reinterpret_cast<ushort4*>(vt2 + tid * 8 + 4) = b;
}

// ---------- fused kernel: 256 blocks x 512 threads (8 waves) ----------
__global__ __launch_bounds__(512, 2) void fused_pattn(
    const float* __restrict__ x,              // [16384][512] fp32
    const unsigned short* __restrict__ kbf,   // [4096][512] bf16 row-major
    const unsigned short* __restrict__ vt2,   // fragment-blocked bf16
    float* __restrict__ out)                  // [16384][512] fp32
{
    // k_lds: LINEAR [64][512] bf16 per buffer (global_load_lds dest must be linear).
    // Data is stored source-pre-swizzled: 16B chunk c of row r holds global chunk c^(r&7).
    __shared__ unsigned short k_lds[2][BM * DDIM];   // 2 x 65536 B
    __shared__ unsigned short g_lds[BM * GPAD];      // 9216 B
    __shared__ float ss_lds[BM];

    const int tid  = threadIdx.x;
    const int lane = tid & 63;
    const int w    = tid >> 6;       // wave 0..7
    const int wr   = w >> 1;         // GEMM1 wave row (0..3)
    const int wc   = w & 1;          // GEMM1 wave col (0..1)
    const int l15  = lane & 15;
    const int l4   = lane >> 4;
    const int m_base = blockIdx.x * BM;

    if (tid < BM) ss_lds[tid] = 0.0f;

    // ---- prologue: issue stage(0) first so its latency overlaps the X load ----
    // Wave w stages rows w*8..w*8+7; one global_load_lds (1024B) per row.
    // Source column chunk for lane = lane ^ (row&7)  (row&7 == i here).
    {
        const int P0 = 0;
        #pragma unroll
        for (int i = 0; i < 8; ++i) {
            int r = w * 8 + i;
            const unsigned short* src = kbf + (size_t)(P0 + r) * DDIM + ((lane ^ i) << 3);
            __builtin_amdgcn_global_load_lds(AS1C(src), AS3(&k_lds[0][r * DDIM]), 16, 0, 0);
        }
    }

    // ---- load X A-fragments once: 16 frags x 8 bf16 (A[l15][l4*8+j]) ----
    bf16x8 xf[16];
    {
        const float* xrow = x + (size_t)(m_base + wr * 16 + l15) * DDIM + l4 * 8;
        #pragma unroll
        for (int db = 0; db < 16; ++db) {
            float4 a = *reinterpret_cast<const float4*>(xrow + db * 32);
            float4 b = *reinterpret_cast<const float4*>(xrow + db * 32 + 4);
            bf16x8 f;
            f[0] = (short)f2bf(a.x); f[1] = (short)f2bf(a.y);
            f[2] = (short)f2bf(a.z); f[3] = (short)f2bf(a.w);
            f[4] = (short)f2bf(b.x); f[5] = (short)f2bf(b.y);
            f[6] = (short)f2bf(b.z); f[7] = (short)f2bf(b.w);
            xf[db] = f;
        }
    }

    f32x4 zero4 = {0.0f, 0.0f, 0.0f, 0.0f};
    f32x4 oacc[4][4];
    #pragma unroll
    for (int i = 0; i < 4; ++i)
        #pragma unroll
        for (int j = 0; j < 4; ++j) oacc[i][j] = zero4;
    float ss[4] = {0.0f, 0.0f, 0.0f, 0.0f};

    int b = 0;
    #pragma unroll 1
    for (int pt = 0; pt < PDIM / BP; ++pt) {
        // ---- A: prefetch V fragments for THIS tile into registers (8 x 16B) ----
        bf16x8 bg[8];
        {
            const int pb0 = pt * 2;
            #pragma unroll
            for (int ks = 0; ks < 2; ++ks)
                #pragma unroll
                for (int nf = 0; nf < 4; ++nf)
                    bg[ks * 4 + nf] = *reinterpret_cast<const bf16x8*>(
                        vt2 + ((size_t)((pb0 + ks) * 32 + w * 4 + nf) * 64 + lane) * 8);
        }

        // ---- B: issue stage(t+1) into the other buffer (wraps on last iter; harmless) ----
        {
            const int P0n = ((pt + 1) & 63) * BP;
            #pragma unroll
            for (int i = 0; i < 8; ++i) {
                int r = w * 8 + i;
                const unsigned short* src = kbf + (size_t)(P0n + r) * DDIM + ((lane ^ i) << 3);
                __builtin_amdgcn_global_load_lds(AS1C(src), AS3(&k_lds[b ^ 1][r * DDIM]), 16, 0, 0);
            }
        }

        // ---- C/D: my stage(t) landed (keep V(t)+stage(t+1) in flight), then all waves' ----
        asm volatile("s_waitcnt vmcnt(16)" ::: "memory");
        __builtin_amdgcn_s_barrier();

        // ---- E: GEMM1  S[64x64] = X @ K^T  (swizzled reads from linear k_lds) ----
        f32x4 sacc[2]; sacc[0] = zero4; sacc[1] = zero4;
        const int swz = (l15 & 7) << 3;                 // elem XOR for this lane's rows
        const unsigned short* kb = &k_lds[b][0];
        __builtin_amdgcn_s_setprio(1);
        #pragma unroll
        for (int db = 0; db < 16; ++db) {
            #pragma unroll
            for (int f = 0; f < 2; ++f) {
                int rowr = wc * 32 + f * 16 + l15;
                int cole = ((db << 5) | (l4 << 3)) ^ swz;
                bf16x8 kv = *reinterpret_cast<const bf16x8*>(kb + rowr * DDIM + cole);
                sacc[f] = __builtin_amdgcn_mfma_f32_16x16x32_bf16(
                    xf[db], kv, sacc[f], 0, 0, 0);
            }
        }
        __builtin_amdgcn_s_setprio(0);

        // ---- F: GELU + sumsq + write g to LDS (bf16) ----
        #pragma unroll
        for (int f = 0; f < 2; ++f) {
            #pragma unroll
            for (int r = 0; r < 4; ++r) {
                float g = gelu_f(sacc[f][r]);
                ss[r] += g * g;
                int m_l = wr * 16 + l4 * 4 + r;
                int p_l = wc * 32 + f * 16 + l15;
                g_lds[m_l * GPAD + p_l] = f2bf(g);
            }
        }
        asm volatile("s_waitcnt lgkmcnt(0)" ::: "memory");
        __builtin_amdgcn_s_barrier();

        // ---- H/I: GEMM2  O += g @ V  (ag from LDS, bg already in regs) ----
        __builtin_amdgcn_s_setprio(1);
        #pragma unroll
        for (int ks = 0; ks < 2; ++ks) {
            bf16x8 ag[4];
            #pragma unroll
            for (int mf = 0; mf < 4; ++mf)
                ag[mf] = *reinterpret_cast<const bf16x8*>(
                    &g_lds[(mf * 16 + l15) * GPAD + ks * 32 + l4 * 8]);
            #pragma unroll
            for (int mf = 0; mf < 4; ++mf)
                #pragma unroll
                for (int nf = 0; nf < 4; ++nf)
                    oacc[mf][nf] = __builtin_amdgcn_mfma_f32_16x16x32_bf16(
                        ag[mf], bg[ks * 4 + nf], oacc[mf][nf], 0, 0, 0);
        }
        __builtin_amdgcn_s_setprio(0);

        b ^= 1;
    }

    // ---- reduce sumsq across the 16 lanes sharing rows, then across wave-cols ----
    #pragma unroll
    for (int r = 0; r < 4; ++r) {
        float v = ss[r];
        v += __shfl_xor(v, 1, 64);
        v += __shfl_xor(v, 2, 64);
        v += __shfl_xor(v, 4, 64);
        v += __shfl_xor(v, 8, 64);
        if (l15 == 0) atomicAdd(&ss_lds[wr * 16 + l4 * 4 + r], v);
    }
    __syncthreads();   // also drains the dangling wrap-stage (vmcnt(0) here is fine/once)

    // ---- epilogue: out = O * sqrt(P)/sqrt(ss) ----
    #pragma unroll
    for (int mf = 0; mf < 4; ++mf) {
        #pragma unroll
        for (int r = 0; r < 4; ++r) {
            int m_l = mf * 16 + l4 * 4 + r;
            float scale = 64.0f * rsqrtf(ss_lds[m_l]);
            float* orow = out + (size_t)(m_base + m_l) * DDIM + w * 64 + l15;
            #pragma unroll
            for (int nf = 0; nf < 4; ++nf)
                orow[nf * 16] = oacc[mf][nf][r] * scale;
        }
    }
}

extern "C" void kernel_launch(void* const* d_in, const int* in_sizes, int n_in,
                              void* d_out, int out_size, void* d_ws, size_t ws_size,
                              hipStream_t stream) {
    const float* x = (const float*)d_in[0];   // [4,4096,512] = [16384][512]
    const float* k = (const float*)d_in[1];   // [4096][512]
    const float* v = (const float*)d_in[2];   // [4096][512]
    float* out = (float*)d_out;               // [16384][512]

    unsigned short* kbf = (unsigned short*)d_ws;            // 4 MB
    unsigned short* vt2 = kbf + (size_t)PDIM * DDIM;        // 4 MB

    conv_k  <<<dim3(2048), dim3(256), 0, stream>>>(k, kbf);
    conv_vt2<<<dim3(1024), dim3(256), 0, stream>>>(v, vt2);
    fused_pattn<<<dim3(M_TOTAL / BM), dim3(512), 0, stream>>>(x, kbf, vt2, out);
}

// Round 3
// 225.595 us; speedup vs baseline: 1.3362x; 1.0062x over previous
//
#include <hip/hip_runtime.h>
#include <hip/hip_bf16.h>

// Pattention fused kernel, round 3: swapped GEMM1 (S^T out) -> packed b64 g-writes,
// lane-local sumsq. Counted-vmcnt pipeline, 2 barriers/tile.
// out[m,n] = (sqrt(P)/||gelu(X K^T)[m,:]||) * (gelu(X K^T) @ V)[m,n]
// M=16384 (B*T), D=512, P=4096. bf16 MFMA (16x16x32), fp32 accum.

typedef __attribute__((ext_vector_type(8))) short bf16x8;   // 8 bf16 = 4 VGPR
typedef __attribute__((ext_vector_type(4))) float f32x4;    // MFMA C/D

static constexpr int M_TOTAL = 16384;
static constexpr int DDIM    = 512;
static constexpr int PDIM    = 4096;
static constexpr int BM      = 64;    // rows per block
static constexpr int BP      = 64;    // P-tile
static constexpr int GPAD    = 72;    // g_lds row elems (64 + 8) -> 144B

#define AS1C(p) ((const __attribute__((address_space(1))) void*)(p))
#define AS3(p)  ((__attribute__((address_space(3))) void*)(p))

__device__ __forceinline__ unsigned short f2bf(float f) {
    union { float f; unsigned u; } v; v.f = f;
    unsigned r = v.u + 0x7FFFu + ((v.u >> 16) & 1u);   // RNE
    return (unsigned short)(r >> 16);
}

// tanh-form GELU: x * sigmoid(2 * x * (c0 + c1 x^2)); |err vs exact| < 1e-3
__device__ __forceinline__ float gelu_f(float x) {
    float t2 = 2.0f * x * (0.7978845608028654f + 0.035677408136300125f * x * x);
    return x / (1.0f + __expf(-t2));
}

// ---------- convert key_tokens fp32 -> bf16 row-major [4096][512] ----------
__global__ void conv_k(const float* __restrict__ kin, unsigned short* __restrict__ kbf) {
    int i = (blockIdx.x * 256 + threadIdx.x) * 4;
    float4 v = *reinterpret_cast<const float4*>(kin + i);
    ushort4 o;
    o.x = f2bf(v.x); o.y = f2bf(v.y); o.z = f2bf(v.z); o.w = f2bf(v.w);
    *reinterpret_cast<ushort4*>(kbf + i) = o;
}

// ---------- convert value_tokens fp32 [4096][512] -> fragment-blocked bf16 ----------
//   vt2[ ((pb*32 + nb)*64 + lane)*8 + j ] = V[ pb*32 + (lane>>4)*8 + j ][ nb*16 + (lane&15) ]
__global__ void conv_vt2(const float* __restrict__ vin, unsigned short* __restrict__ vt2) {
    int tid  = blockIdx.x * 256 + threadIdx.x;  // 262144 total
    int lane = tid & 63;
    int blk  = tid >> 6;
    int nb = blk & 31;
    int pb = blk >> 5;
    int p0 = pb * 32 + ((lane >> 4) << 3);
    int n  = nb * 16 + (lane & 15);
    ushort4 a, b;
    a.x = f2bf(vin[(p0 + 0) * DDIM + n]);
    a.y = f2bf(vin[(p0 + 1) * DDIM + n]);
    a.z = f2bf(vin[(p0 + 2) * DDIM + n]);
    a.w = f2bf(vin[(p0 + 3) * DDIM + n]);
    b.x = f2bf(vin[(p0 + 4) * DDIM + n]);
    b.y = f2bf(vin[(p0 + 5) * DDIM + n]);
    b.z = f2bf(vin[(p0 + 6) * DDIM + n]);
    b.w = f2bf(vin[(p0 + 7) * DDIM + n]);
    *reinterpret_cast<ushort4*>(vt2 + tid * 8 + 0) = a;
    *reinterpret_cast<ushort4*>(vt2 + tid * 8 + 4) = b;
}

// ---------- fused kernel: 256 blocks x 512 threads (8 waves) ----------
// GEMM1 (swapped): wave (wm = w>>1, wp = w&1) computes S^T[p=wp*32..+32][m=wm*16..+16].
// GEMM2: wave w owns output cols [64w, 64w+64).
__global__ __launch_bounds__(512, 2) void fused_pattn(
    const float* __restrict__ x,              // [16384][512] fp32
    const unsigned short* __restrict__ kbf,   // [4096][512] bf16 row-major
    const unsigned short* __restrict__ vt2,   // fragment-blocked bf16
    float* __restrict__ out)                  // [16384][512] fp32
{
    // k_lds: LINEAR [64][512] bf16 per buffer; source-pre-swizzled so reads XOR.
    __shared__ unsigned short k_lds[2][BM * DDIM];   // 2 x 65536 B
    __shared__ unsigned short g_lds[BM * GPAD];      // 9216 B
    __shared__ float ss_lds[BM];

    const int tid  = threadIdx.x;
    const int lane = tid & 63;
    const int w    = tid >> 6;       // wave 0..7
    const int wm   = w >> 1;         // GEMM1 m-block (0..3)
    const int wp   = w & 1;          // GEMM1 p-block (0..1)
    const int l15  = lane & 15;
    const int l4   = lane >> 4;
    const int m_base = blockIdx.x * BM;

    if (tid < BM) ss_lds[tid] = 0.0f;

    // ---- prologue: issue stage(0) first so its latency overlaps the X load ----
    {
        const int P0 = 0;
        #pragma unroll
        for (int i = 0; i < 8; ++i) {
            int r = w * 8 + i;
            const unsigned short* src = kbf + (size_t)(P0 + r) * DDIM + ((lane ^ i) << 3);
            __builtin_amdgcn_global_load_lds(AS1C(src), AS3(&k_lds[0][r * DDIM]), 16, 0, 0);
        }
    }

    // ---- load X fragments once: 16 frags x 8 bf16, X[wm*16 + l15][db*32 + l4*8 + j] ----
    bf16x8 xf[16];
    {
        const float* xrow = x + (size_t)(m_base + wm * 16 + l15) * DDIM + l4 * 8;
        #pragma unroll
        for (int db = 0; db < 16; ++db) {
            float4 a = *reinterpret_cast<const float4*>(xrow + db * 32);
            float4 b = *reinterpret_cast<const float4*>(xrow + db * 32 + 4);
            bf16x8 f;
            f[0] = (short)f2bf(a.x); f[1] = (short)f2bf(a.y);
            f[2] = (short)f2bf(a.z); f[3] = (short)f2bf(a.w);
            f[4] = (short)f2bf(b.x); f[5] = (short)f2bf(b.y);
            f[6] = (short)f2bf(b.z); f[7] = (short)f2bf(b.w);
            xf[db] = f;
        }
    }

    f32x4 zero4 = {0.0f, 0.0f, 0.0f, 0.0f};
    f32x4 oacc[4][4];
    #pragma unroll
    for (int i = 0; i < 4; ++i)
        #pragma unroll
        for (int j = 0; j < 4; ++j) oacc[i][j] = zero4;
    float ss = 0.0f;   // lane-local sum of g^2 (all values share row m = wm*16+l15)

    int b = 0;
    #pragma unroll 1
    for (int pt = 0; pt < PDIM / BP; ++pt) {
        // ---- A: prefetch V fragments for THIS tile into registers (8 x 16B) ----
        bf16x8 bg[8];
        {
            const int pb0 = pt * 2;
            #pragma unroll
            for (int ks = 0; ks < 2; ++ks)
                #pragma unroll
                for (int nf = 0; nf < 4; ++nf)
                    bg[ks * 4 + nf] = *reinterpret_cast<const bf16x8*>(
                        vt2 + ((size_t)((pb0 + ks) * 32 + w * 4 + nf) * 64 + lane) * 8);
        }

        // ---- B: issue stage(t+1) into the other buffer (wraps on last iter; harmless) ----
        {
            const int P0n = ((pt + 1) & 63) * BP;
            #pragma unroll
            for (int i = 0; i < 8; ++i) {
                int r = w * 8 + i;
                const unsigned short* src = kbf + (size_t)(P0n + r) * DDIM + ((lane ^ i) << 3);
                __builtin_amdgcn_global_load_lds(AS1C(src), AS3(&k_lds[b ^ 1][r * DDIM]), 16, 0, 0);
            }
        }

        // ---- C/D: my stage(t) landed (keep bg(t)+stage(t+1) in flight), then all waves' ----
        asm volatile("s_waitcnt vmcnt(16)" ::: "memory");
        __builtin_amdgcn_s_barrier();

        // ---- E: GEMM1 swapped: sacc[f] = S^T tile (p = wp*32+f*16+l4*4+r, m = wm*16+l15) ----
        f32x4 sacc[2]; sacc[0] = zero4; sacc[1] = zero4;
        const int swz = (l15 & 7) << 3;                 // elem XOR for this lane's rows
        const unsigned short* kb = &k_lds[b][0];
        __builtin_amdgcn_s_setprio(1);
        #pragma unroll
        for (int db = 0; db < 16; ++db) {
            #pragma unroll
            for (int f = 0; f < 2; ++f) {
                int rowr = wp * 32 + f * 16 + l15;      // K row (p)
                int cole = ((db << 5) | (l4 << 3)) ^ swz;
                bf16x8 kv = *reinterpret_cast<const bf16x8*>(kb + rowr * DDIM + cole);
                sacc[f] = __builtin_amdgcn_mfma_f32_16x16x32_bf16(
                    kv, xf[db], sacc[f], 0, 0, 0);      // swapped: D = K_rows . X^T = S^T
            }
        }
        __builtin_amdgcn_s_setprio(0);

        // ---- F: GELU + lane-local sumsq + packed b64 g-writes ----
        #pragma unroll
        for (int f = 0; f < 2; ++f) {
            float g0 = gelu_f(sacc[f][0]);
            float g1 = gelu_f(sacc[f][1]);
            float g2 = gelu_f(sacc[f][2]);
            float g3 = gelu_f(sacc[f][3]);
            ss += g0 * g0 + g1 * g1 + g2 * g2 + g3 * g3;
            unsigned d0 = (unsigned)f2bf(g0) | ((unsigned)f2bf(g1) << 16);
            unsigned d1 = (unsigned)f2bf(g2) | ((unsigned)f2bf(g3) << 16);
            int m_l = wm * 16 + l15;
            int p_l = wp * 32 + f * 16 + l4 * 4;        // 4 consecutive p -> 8B store
            *reinterpret_cast<uint2*>(&g_lds[m_l * GPAD + p_l]) = make_uint2(d0, d1);
        }
        asm volatile("s_waitcnt lgkmcnt(0)" ::: "memory");
        __builtin_amdgcn_s_barrier();

        // ---- H: GEMM2  O += g @ V  (ag from LDS, bg already in regs) ----
        __builtin_amdgcn_s_setprio(1);
        #pragma unroll
        for (int ks = 0; ks < 2; ++ks) {
            bf16x8 ag[4];
            #pragma unroll
            for (int mf = 0; mf < 4; ++mf)
                ag[mf] = *reinterpret_cast<const bf16x8*>(
                    &g_lds[(mf * 16 + l15) * GPAD + ks * 32 + l4 * 8]);
            #pragma unroll
            for (int mf = 0; mf < 4; ++mf)
                #pragma unroll
                for (int nf = 0; nf < 4; ++nf)
                    oacc[mf][nf] = __builtin_amdgcn_mfma_f32_16x16x32_bf16(
                        ag[mf], bg[ks * 4 + nf], oacc[mf][nf], 0, 0, 0);
        }
        __builtin_amdgcn_s_setprio(0);

        b ^= 1;
    }

    // ---- sumsq: reduce across the 4 lane-groups sharing each row, then across wp waves ----
    {
        float v = ss;
        v += __shfl_xor(v, 16, 64);
        v += __shfl_xor(v, 32, 64);
        if (l4 == 0) atomicAdd(&ss_lds[wm * 16 + l15], v);
    }
    __syncthreads();   // ss ready; also drains the dangling wrap-stage

    // ---- epilogue: out = O * sqrt(P)/sqrt(ss) ----
    #pragma unroll
    for (int mf = 0; mf < 4; ++mf) {
        #pragma unroll
        for (int r = 0; r < 4; ++r) {
            int m_l = mf * 16 + l4 * 4 + r;
            float scale = 64.0f * rsqrtf(ss_lds[m_l]);
            float* orow = out + (size_t)(m_base + m_l) * DDIM + w * 64 + l15;
            #pragma unroll
            for (int nf = 0; nf < 4; ++nf)
                orow[nf * 16] = oacc[mf][nf][r] * scale;
        }
    }
}

extern "C" void kernel_launch(void* const* d_in, const int* in_sizes, int n_in,
                              void* d_out, int out_size, void* d_ws, size_t ws_size,
                              hipStream_t stream) {
    const float* x = (const float*)d_in[0];   // [4,4096,512] = [16384][512]
    const float* k = (const float*)d_in[1];   // [4096][512]
    const float* v = (const float*)d_in[2];   // [4096][512]
    float* out = (float*)d_out;               // [16384][512]

    unsigned short* kbf = (unsigned short*)d_ws;            // 4 MB
    unsigned short* vt2 = kbf + (size_t)PDIM * DDIM;        // 4 MB

    conv_k  <<<dim3(2048), dim3(256), 0, stream>>>(k, kbf);
    conv_vt2<<<dim3(1024), dim3(256), 0, stream>>>(v, vt2);
    fused_pattn<<<dim3(M_TOTAL / BM), dim3(512), 0, stream>>>(x, kbf, vt2, out);
}